// Round 3
// baseline (1158.067 us; speedup 1.0000x reference)
//
#include <hip/hip_runtime.h>

#define IN_C 256
#define HIDC 32
#define OUTC 16
#define NPB  128          // nodes per bucket
#define MAXBKT 800        // >= ceil(100000/128) = 782

// ---------------- edge index loader (handles int32 or int64 storage) -------
__device__ __forceinline__ int edge_at(const int* __restrict__ ei, long long idx, int is64) {
    return is64 ? ei[idx << 1] : ei[idx];
}

// Detect int64 vs int32 storage: sample odd 32-bit words; all-zero => int64.
__global__ void k_detect(const int* __restrict__ ei, int* __restrict__ flag) {
    __shared__ int nz;
    if (threadIdx.x == 0) nz = 0;
    __syncthreads();
    if (ei[2 * threadIdx.x + 1] != 0) atomicOr(&nz, 1);
    __syncthreads();
    if (threadIdx.x == 0) *flag = (nz == 0) ? 1 : 0;
}

// ---------------- bucket binning (counting sort to 782 buckets) ------------
// pass 1: per-block LDS histogram -> global bucket counts
__global__ __launch_bounds__(256) void k_bin_count(const int* __restrict__ ei, long long E,
                                                   const int* __restrict__ flag,
                                                   int* __restrict__ bkt_cnt, int nbkt) {
    __shared__ int hist[MAXBKT];
    int is64 = *flag;
    for (int i = threadIdx.x; i < nbkt; i += 256) hist[i] = 0;
    __syncthreads();
    long long chunk = (E + gridDim.x - 1) / gridDim.x;
    long long lo = (long long)blockIdx.x * chunk;
    long long hi = lo + chunk; if (hi > E) hi = E;
    for (long long i = lo + threadIdx.x; i < hi; i += 256)
        atomicAdd(&hist[edge_at(ei, E + i, is64) >> 7], 1);
    __syncthreads();
    for (int b = threadIdx.x; b < nbkt; b += 256)
        if (hist[b]) atomicAdd(&bkt_cnt[b], hist[b]);
}

// scan over nbkt (<=1024) bucket counts, single block of 512 threads, 2/thread
__global__ __launch_bounds__(512) void k_bscan(const int* __restrict__ bkt_cnt,
                                               int* __restrict__ bkt_base,
                                               int* __restrict__ bkt_cur, int nbkt) {
    __shared__ int sm[512];
    int t = threadIdx.x;
    int e0 = (2 * t < nbkt) ? bkt_cnt[2 * t] : 0;
    int e1 = (2 * t + 1 < nbkt) ? bkt_cnt[2 * t + 1] : 0;
    int pv = e0 + e1;
    sm[t] = pv;
    __syncthreads();
    for (int o = 1; o < 512; o <<= 1) {
        int x = (t >= o) ? sm[t - o] : 0;
        __syncthreads();
        sm[t] += x;
        __syncthreads();
    }
    int base = sm[t] - pv;  // exclusive over pairs
    if (2 * t < nbkt)     { bkt_base[2 * t] = base;      bkt_cur[2 * t] = base; }
    if (2 * t + 1 < nbkt) { bkt_base[2 * t + 1] = base + e0; bkt_cur[2 * t + 1] = base + e0; }
}

// pass 2: reserve per-(block,bucket) ranges, write packed (d_local<<20 | src)
__global__ __launch_bounds__(256) void k_bin_scatter(const int* __restrict__ ei, long long E,
                                                     const int* __restrict__ flag,
                                                     int* __restrict__ bkt_cur,
                                                     unsigned* __restrict__ packed, int nbkt) {
    __shared__ int hist[MAXBKT];
    int is64 = *flag;
    for (int i = threadIdx.x; i < nbkt; i += 256) hist[i] = 0;
    __syncthreads();
    long long chunk = (E + gridDim.x - 1) / gridDim.x;
    long long lo = (long long)blockIdx.x * chunk;
    long long hi = lo + chunk; if (hi > E) hi = E;
    for (long long i = lo + threadIdx.x; i < hi; i += 256)
        atomicAdd(&hist[edge_at(ei, E + i, is64) >> 7], 1);
    __syncthreads();
    for (int b = threadIdx.x; b < nbkt; b += 256) {
        int c = hist[b];
        hist[b] = c ? atomicAdd(&bkt_cur[b], c) : 0;   // hist now = running cursor
    }
    __syncthreads();
    for (long long i = lo + threadIdx.x; i < hi; i += 256) {
        int s = edge_at(ei, i, is64);
        int d = edge_at(ei, E + i, is64);
        int slot = atomicAdd(&hist[d >> 7], 1);
        packed[slot] = (unsigned)s | ((unsigned)(d & (NPB - 1)) << 20);
    }
}

// per-bucket degree histogram -> dinv = rsqrt(deg+1)
__global__ __launch_bounds__(256) void k_degdinv(const unsigned* __restrict__ packed,
                                                 const int* __restrict__ bkt_base,
                                                 const int* __restrict__ bkt_cnt,
                                                 float* __restrict__ dinv, int n) {
    __shared__ int cnt[NPB];
    if (threadIdx.x < NPB) cnt[threadIdx.x] = 0;
    __syncthreads();
    int base = bkt_base[blockIdx.x], m = bkt_cnt[blockIdx.x];
    for (int i = threadIdx.x; i < m; i += 256)
        atomicAdd(&cnt[packed[base + i] >> 20], 1);
    __syncthreads();
    int node = blockIdx.x * NPB + threadIdx.x;
    if (threadIdx.x < NPB && node < n)
        dinv[node] = rsqrtf((float)cnt[threadIdx.x] + 1.0f);
}

// ---------------- gemm1: h1 = x @ W1  [n,256]x[256,32] ---------------------
#define G1_KC 32
__global__ __launch_bounds__(256) void k_gemm1(const float* __restrict__ x,
                                               const float* __restrict__ W1,
                                               float* __restrict__ h1, int n) {
    __shared__ float xs[256][40];
    const int t = threadIdx.x;
    const int node = blockIdx.x * 256 + t;
    float acc[HIDC];
#pragma unroll
    for (int o = 0; o < HIDC; ++o) acc[o] = 0.f;

    for (int k0 = 0; k0 < IN_C; k0 += G1_KC) {
#pragma unroll
        for (int it = 0; it < 8; ++it) {
            int i = it * 256 + t;
            int row = i >> 3;
            int c4 = i & 7;
            int gnode = blockIdx.x * 256 + row;
            float4 v = make_float4(0.f, 0.f, 0.f, 0.f);
            if (gnode < n)
                v = *(const float4*)(x + (long long)gnode * IN_C + k0 + c4 * 4);
            *(float4*)&xs[row][c4 * 4] = v;
        }
        __syncthreads();
        float xr[G1_KC];
#pragma unroll
        for (int j = 0; j < 8; ++j) {
            float4 v = *(const float4*)&xs[t][j * 4];
            xr[j * 4 + 0] = v.x; xr[j * 4 + 1] = v.y;
            xr[j * 4 + 2] = v.z; xr[j * 4 + 3] = v.w;
        }
#pragma unroll
        for (int kk = 0; kk < G1_KC; ++kk) {
            const float* __restrict__ wrow = W1 + (long long)(k0 + kk) * HIDC;
#pragma unroll
            for (int o = 0; o < HIDC; ++o)
                acc[o] = fmaf(xr[kk], wrow[o], acc[o]);
        }
        __syncthreads();
    }
    if (node < n) {
#pragma unroll
        for (int j = 0; j < 8; ++j)
            *(float4*)(h1 + (long long)node * HIDC + j * 4) =
                make_float4(acc[j * 4], acc[j * 4 + 1], acc[j * 4 + 2], acc[j * 4 + 3]);
    }
}

// ---------------- layer-1 bucket aggregation in LDS + fused finalize -------
// one block per bucket; half-wave (32 lanes = 32 ch) per edge; ds_add_f32 acc.
__global__ __launch_bounds__(256) void k_agg1b(const unsigned* __restrict__ packed,
                                               const int* __restrict__ bkt_base,
                                               const int* __restrict__ bkt_cnt,
                                               const float* __restrict__ dinv,
                                               const float* __restrict__ h1,
                                               const float* __restrict__ b1,
                                               float* __restrict__ h1r, int n) {
    __shared__ float acc[NPB * HIDC];  // 16 KB
    for (int i = threadIdx.x; i < NPB * HIDC; i += 256) acc[i] = 0.f;
    __syncthreads();
    int base = bkt_base[blockIdx.x], m = bkt_cnt[blockIdx.x];
    int ch = threadIdx.x & 31, hw = threadIdx.x >> 5;  // 8 half-waves
    int i = hw;
    for (; i + 24 < m; i += 32) {
        unsigned w0 = packed[base + i], w1 = packed[base + i + 8];
        unsigned w2 = packed[base + i + 16], w3 = packed[base + i + 24];
        int s0 = w0 & 0xFFFFF, s1 = w1 & 0xFFFFF, s2 = w2 & 0xFFFFF, s3 = w3 & 0xFFFFF;
        float d0 = dinv[s0], d1 = dinv[s1], d2 = dinv[s2], d3 = dinv[s3];
        float v0 = h1[(long long)s0 * HIDC + ch] * d0;
        float v1 = h1[(long long)s1 * HIDC + ch] * d1;
        float v2 = h1[(long long)s2 * HIDC + ch] * d2;
        float v3 = h1[(long long)s3 * HIDC + ch] * d3;
        atomicAdd(&acc[(w0 >> 20) * HIDC + ch], v0);
        atomicAdd(&acc[(w1 >> 20) * HIDC + ch], v1);
        atomicAdd(&acc[(w2 >> 20) * HIDC + ch], v2);
        atomicAdd(&acc[(w3 >> 20) * HIDC + ch], v3);
    }
    for (; i < m; i += 8) {
        unsigned w = packed[base + i];
        int s = w & 0xFFFFF;
        float v = h1[(long long)s * HIDC + ch] * dinv[s];
        atomicAdd(&acc[(w >> 20) * HIDC + ch], v);
    }
    __syncthreads();
    long long nb0 = (long long)blockIdx.x * NPB;
#pragma unroll
    for (int j = 0; j < NPB * HIDC / 256; ++j) {  // 16 iters
        int lin = j * 256 + threadIdx.x;
        int nl = lin >> 5, c2 = lin & 31;
        long long node = nb0 + nl;
        if (node < n) {
            float di = dinv[node];
            float v = (acc[lin] + h1[node * HIDC + c2] * di) * di + b1[c2];
            h1r[node * HIDC + c2] = v > 0.f ? v : 0.f;
        }
    }
}

// ---------------- gemm2: h2 = h1r @ W2  [n,32]x[32,16] ---------------------
__global__ __launch_bounds__(256) void k_gemm2(const float* __restrict__ h1,
                                               const float* __restrict__ W2,
                                               float* __restrict__ h2, int n) {
    int node = blockIdx.x * 256 + threadIdx.x;
    if (node >= n) return;
    float xr[HIDC];
#pragma unroll
    for (int j = 0; j < 8; ++j) {
        float4 v = *(const float4*)(h1 + (long long)node * HIDC + j * 4);
        xr[j * 4 + 0] = v.x; xr[j * 4 + 1] = v.y;
        xr[j * 4 + 2] = v.z; xr[j * 4 + 3] = v.w;
    }
    float acc[OUTC];
#pragma unroll
    for (int o = 0; o < OUTC; ++o) acc[o] = 0.f;
#pragma unroll
    for (int kk = 0; kk < HIDC; ++kk) {
        const float* __restrict__ wrow = W2 + kk * OUTC;
#pragma unroll
        for (int o = 0; o < OUTC; ++o)
            acc[o] = fmaf(xr[kk], wrow[o], acc[o]);
    }
#pragma unroll
    for (int j = 0; j < 4; ++j)
        *(float4*)(h2 + (long long)node * OUTC + j * 4) =
            make_float4(acc[j * 4], acc[j * 4 + 1], acc[j * 4 + 2], acc[j * 4 + 3]);
}

// ---------------- layer-2 bucket aggregation -> d_out ----------------------
// quarter-wave (16 lanes = 16 ch) per edge.
__global__ __launch_bounds__(256) void k_agg2b(const unsigned* __restrict__ packed,
                                               const int* __restrict__ bkt_base,
                                               const int* __restrict__ bkt_cnt,
                                               const float* __restrict__ dinv,
                                               const float* __restrict__ h2,
                                               const float* __restrict__ b2,
                                               float* __restrict__ out, int n) {
    __shared__ float acc[NPB * OUTC];  // 8 KB
    for (int i = threadIdx.x; i < NPB * OUTC; i += 256) acc[i] = 0.f;
    __syncthreads();
    int base = bkt_base[blockIdx.x], m = bkt_cnt[blockIdx.x];
    int ch = threadIdx.x & 15, qw = threadIdx.x >> 4;  // 16 quarter-waves
    int i = qw;
    for (; i + 48 < m; i += 64) {
        unsigned w0 = packed[base + i], w1 = packed[base + i + 16];
        unsigned w2 = packed[base + i + 32], w3 = packed[base + i + 48];
        int s0 = w0 & 0xFFFFF, s1 = w1 & 0xFFFFF, s2 = w2 & 0xFFFFF, s3 = w3 & 0xFFFFF;
        float d0 = dinv[s0], d1 = dinv[s1], d2 = dinv[s2], d3 = dinv[s3];
        float v0 = h2[(long long)s0 * OUTC + ch] * d0;
        float v1 = h2[(long long)s1 * OUTC + ch] * d1;
        float v2 = h2[(long long)s2 * OUTC + ch] * d2;
        float v3 = h2[(long long)s3 * OUTC + ch] * d3;
        atomicAdd(&acc[(w0 >> 20) * OUTC + ch], v0);
        atomicAdd(&acc[(w1 >> 20) * OUTC + ch], v1);
        atomicAdd(&acc[(w2 >> 20) * OUTC + ch], v2);
        atomicAdd(&acc[(w3 >> 20) * OUTC + ch], v3);
    }
    for (; i < m; i += 16) {
        unsigned w = packed[base + i];
        int s = w & 0xFFFFF;
        float v = h2[(long long)s * OUTC + ch] * dinv[s];
        atomicAdd(&acc[(w >> 20) * OUTC + ch], v);
    }
    __syncthreads();
    long long nb0 = (long long)blockIdx.x * NPB;
#pragma unroll
    for (int j = 0; j < NPB * OUTC / 256; ++j) {  // 8 iters
        int lin = j * 256 + threadIdx.x;
        int nl = lin >> 4, c2 = lin & 15;
        long long node = nb0 + nl;
        if (node < n) {
            float di = dinv[node];
            out[node * OUTC + c2] = (acc[lin] + h2[node * OUTC + c2] * di) * di + b2[c2];
        }
    }
}

extern "C" void kernel_launch(void* const* d_in, const int* in_sizes, int n_in,
                              void* d_out, int out_size, void* d_ws, size_t ws_size,
                              hipStream_t stream) {
    const float* x  = (const float*)d_in[0];
    const int*   ei = (const int*)d_in[1];
    const float* W1 = (const float*)d_in[2];
    const float* b1 = (const float*)d_in[3];
    const float* W2 = (const float*)d_in[4];
    const float* b2 = (const float*)d_in[5];
    const int n = in_sizes[0] / IN_C;            // 100000
    const long long E = in_sizes[1] / 2;         // 3200000
    float* out = (float*)d_out;

    const int nbkt = (n + NPB - 1) / NPB;        // 782 (<= MAXBKT, <= 1024)

    char* ws = (char*)d_ws;
    size_t off = 0;
    auto alloc = [&](size_t bytes) { void* p = ws + off; off += (bytes + 255) & ~(size_t)255; return p; };
    int*      flag     = (int*)alloc(256);
    int*      bkt_cnt  = (int*)alloc((size_t)MAXBKT * 4);
    int*      bkt_base = (int*)alloc((size_t)MAXBKT * 4);
    int*      bkt_cur  = (int*)alloc((size_t)MAXBKT * 4);
    float*    dinv     = (float*)alloc((size_t)n * 4);
    unsigned* packed   = (unsigned*)alloc((size_t)E * 4);
    float*    h1       = (float*)alloc((size_t)n * HIDC * 4);
    float*    h1r      = (float*)alloc((size_t)n * HIDC * 4);
    float*    h2       = h1;  // h1 (pre-relu) dead after k_agg1b; reuse

    hipMemsetAsync(bkt_cnt, 0, (size_t)nbkt * 4, stream);

    k_detect<<<1, 256, 0, stream>>>(ei, flag);
    k_bin_count<<<256, 256, 0, stream>>>(ei, E, flag, bkt_cnt, nbkt);
    k_bscan<<<1, 512, 0, stream>>>(bkt_cnt, bkt_base, bkt_cur, nbkt);
    k_bin_scatter<<<256, 256, 0, stream>>>(ei, E, flag, bkt_cur, packed, nbkt);
    k_degdinv<<<nbkt, 256, 0, stream>>>(packed, bkt_base, bkt_cnt, dinv, n);

    k_gemm1<<<(n + 255) / 256, 256, 0, stream>>>(x, W1, h1, n);
    k_agg1b<<<nbkt, 256, 0, stream>>>(packed, bkt_base, bkt_cnt, dinv, h1, b1, h1r, n);
    k_gemm2<<<(n + 255) / 256, 256, 0, stream>>>(h1r, W2, h2, n);
    k_agg2b<<<nbkt, 256, 0, stream>>>(packed, bkt_base, bkt_cnt, dinv, h2, b2, out, n);
}

// Round 4
// 273.752 us; speedup vs baseline: 4.2304x; 4.2304x over previous
//
#include <hip/hip_runtime.h>

#define IN_C 256
#define HIDC 32
#define OUTC 16
#define NPB  128          // nodes per bucket (d_local = 7 bits)
#define MAXBKT 800        // >= ceil(100000/128) = 782

// ---------------- edge index loader (handles int32 or int64 storage) -------
__device__ __forceinline__ int edge_at(const int* __restrict__ ei, long long idx, int is64) {
    return is64 ? ei[idx << 1] : ei[idx];
}

// Detect int64 vs int32 storage: sample odd 32-bit words; all-zero => int64.
__global__ void k_detect(const int* __restrict__ ei, int* __restrict__ flag) {
    __shared__ int nz;
    if (threadIdx.x == 0) nz = 0;
    __syncthreads();
    if (ei[2 * threadIdx.x + 1] != 0) atomicOr(&nz, 1);
    __syncthreads();
    if (threadIdx.x == 0) *flag = (nz == 0) ? 1 : 0;
}

// ---------------- bucket binning -------------------------------------------
// pass 1: per-block LDS histogram of dst-buckets -> global bucket counts
__global__ __launch_bounds__(256) void k_bin_count(const int* __restrict__ ei, long long E,
                                                   const int* __restrict__ flag,
                                                   int* __restrict__ bkt_cnt, int nbkt) {
    __shared__ int hist[MAXBKT];
    int is64 = *flag;
    for (int i = threadIdx.x; i < nbkt; i += 256) hist[i] = 0;
    __syncthreads();
    long long chunk = (E + gridDim.x - 1) / gridDim.x;
    long long lo = (long long)blockIdx.x * chunk;
    long long hi = lo + chunk; if (hi > E) hi = E;
    for (long long i = lo + threadIdx.x; i < hi; i += 256)
        atomicAdd(&hist[edge_at(ei, E + i, is64) >> 7], 1);
    __syncthreads();
    for (int b = threadIdx.x; b < nbkt; b += 256)
        if (hist[b]) atomicAdd(&bkt_cnt[b], hist[b]);
}

// scan over nbkt (<=1024) bucket counts, single block of 512 threads, 2/thread
__global__ __launch_bounds__(512) void k_bscan(const int* __restrict__ bkt_cnt,
                                               int* __restrict__ bkt_base,
                                               int* __restrict__ bkt_cur, int nbkt) {
    __shared__ int sm[512];
    int t = threadIdx.x;
    int e0 = (2 * t < nbkt) ? bkt_cnt[2 * t] : 0;
    int e1 = (2 * t + 1 < nbkt) ? bkt_cnt[2 * t + 1] : 0;
    int pv = e0 + e1;
    sm[t] = pv;
    __syncthreads();
    for (int o = 1; o < 512; o <<= 1) {
        int x = (t >= o) ? sm[t - o] : 0;
        __syncthreads();
        sm[t] += x;
        __syncthreads();
    }
    int base = sm[t] - pv;  // exclusive over pairs
    if (2 * t < nbkt)     { bkt_base[2 * t] = base;          bkt_cur[2 * t] = base; }
    if (2 * t + 1 < nbkt) { bkt_base[2 * t + 1] = base + e0; bkt_cur[2 * t + 1] = base + e0; }
}

// pass 2: reserve per-(block,bucket) ranges, write packed (d_local<<20 | src)
// writes are clustered runs per (block,bucket) -> ~64B granularity
__global__ __launch_bounds__(256) void k_bin_scatter(const int* __restrict__ ei, long long E,
                                                     const int* __restrict__ flag,
                                                     int* __restrict__ bkt_cur,
                                                     unsigned* __restrict__ packed, int nbkt) {
    __shared__ int hist[MAXBKT];
    int is64 = *flag;
    for (int i = threadIdx.x; i < nbkt; i += 256) hist[i] = 0;
    __syncthreads();
    long long chunk = (E + gridDim.x - 1) / gridDim.x;
    long long lo = (long long)blockIdx.x * chunk;
    long long hi = lo + chunk; if (hi > E) hi = E;
    for (long long i = lo + threadIdx.x; i < hi; i += 256)
        atomicAdd(&hist[edge_at(ei, E + i, is64) >> 7], 1);
    __syncthreads();
    for (int b = threadIdx.x; b < nbkt; b += 256) {
        int c = hist[b];
        hist[b] = c ? atomicAdd(&bkt_cur[b], c) : 0;   // hist now = running cursor
    }
    __syncthreads();
    for (long long i = lo + threadIdx.x; i < hi; i += 256) {
        int s = edge_at(ei, i, is64);
        int d = edge_at(ei, E + i, is64);
        int slot = atomicAdd(&hist[d >> 7], 1);
        packed[slot] = (unsigned)s | ((unsigned)(d & (NPB - 1)) << 20);
    }
}

// ---------------- per-bucket counting sort -> node-level CSR ---------------
// one block per bucket; all reads/writes inside the bucket's contiguous range.
// also emits ptr/cnt/dinv per node (replaces k_count + k_degdinv).
__global__ __launch_bounds__(256) void k_bucket_csr(const unsigned* __restrict__ packed,
                                                    const int* __restrict__ bkt_base,
                                                    const int* __restrict__ bkt_cnt,
                                                    int* __restrict__ csr_src,
                                                    int* __restrict__ ptr,
                                                    int* __restrict__ cnt,
                                                    float* __restrict__ dinv, int n) {
    __shared__ int hist[NPB];
    __shared__ int off[NPB];
    if (threadIdx.x < NPB) hist[threadIdx.x] = 0;
    __syncthreads();
    int base = bkt_base[blockIdx.x], m = bkt_cnt[blockIdx.x];
    for (int i = threadIdx.x; i < m; i += 256)
        atomicAdd(&hist[packed[base + i] >> 20], 1);
    __syncthreads();
    if (threadIdx.x < NPB) off[threadIdx.x] = hist[threadIdx.x];
    __syncthreads();
    for (int o = 1; o < NPB; o <<= 1) {           // inclusive scan over 128 bins
        int v = 0;
        if (threadIdx.x < NPB && threadIdx.x >= o) v = off[threadIdx.x - o];
        __syncthreads();
        if (threadIdx.x < NPB) off[threadIdx.x] += v;
        __syncthreads();
    }
    int node = blockIdx.x * NPB + threadIdx.x;
    if (threadIdx.x < NPB) {
        int exc = off[threadIdx.x] - hist[threadIdx.x];
        if (node < n) {
            ptr[node]  = base + exc;
            cnt[node]  = hist[threadIdx.x];
            dinv[node] = rsqrtf((float)hist[threadIdx.x] + 1.0f);
        }
        hist[threadIdx.x] = exc;                  // reuse as cursor
    }
    __syncthreads();
    for (int i = threadIdx.x; i < m; i += 256) {
        unsigned w = packed[base + i];
        int r = atomicAdd(&hist[w >> 20], 1);
        csr_src[base + r] = (int)(w & 0xFFFFF);   // write inside bucket window
    }
}

// ---------------- gemm1: h1s = (x @ W1) * dinv  [n,256]x[256,32] ------------
#define G1_KC 32
__global__ __launch_bounds__(256) void k_gemm1(const float* __restrict__ x,
                                               const float* __restrict__ W1,
                                               const float* __restrict__ dinv,
                                               float* __restrict__ h1s, int n) {
    __shared__ float xs[256][40];
    const int t = threadIdx.x;
    const int node = blockIdx.x * 256 + t;
    float acc[HIDC];
#pragma unroll
    for (int o = 0; o < HIDC; ++o) acc[o] = 0.f;

    for (int k0 = 0; k0 < IN_C; k0 += G1_KC) {
#pragma unroll
        for (int it = 0; it < 8; ++it) {
            int i = it * 256 + t;
            int row = i >> 3;
            int c4 = i & 7;
            int gnode = blockIdx.x * 256 + row;
            float4 v = make_float4(0.f, 0.f, 0.f, 0.f);
            if (gnode < n)
                v = *(const float4*)(x + (long long)gnode * IN_C + k0 + c4 * 4);
            *(float4*)&xs[row][c4 * 4] = v;
        }
        __syncthreads();
        float xr[G1_KC];
#pragma unroll
        for (int j = 0; j < 8; ++j) {
            float4 v = *(const float4*)&xs[t][j * 4];
            xr[j * 4 + 0] = v.x; xr[j * 4 + 1] = v.y;
            xr[j * 4 + 2] = v.z; xr[j * 4 + 3] = v.w;
        }
#pragma unroll
        for (int kk = 0; kk < G1_KC; ++kk) {
            const float* __restrict__ wrow = W1 + (long long)(k0 + kk) * HIDC;
#pragma unroll
            for (int o = 0; o < HIDC; ++o)
                acc[o] = fmaf(xr[kk], wrow[o], acc[o]);
        }
        __syncthreads();
    }
    if (node < n) {
        float di = dinv[node];
#pragma unroll
        for (int j = 0; j < 8; ++j)
            *(float4*)(h1s + (long long)node * HIDC + j * 4) =
                make_float4(acc[j * 4] * di, acc[j * 4 + 1] * di,
                            acc[j * 4 + 2] * di, acc[j * 4 + 3] * di);
    }
}

// ---------------- layer-1 pull aggregation + fused finalize ----------------
// half-wave (32 lanes = 32 ch) per dst node; h1s rows are pre-scaled by dinv.
__global__ __launch_bounds__(256) void k_agg1csr(const int* __restrict__ ptr,
                                                 const int* __restrict__ cnt,
                                                 const int* __restrict__ csr_src,
                                                 const float* __restrict__ dinv,
                                                 const float* __restrict__ h1s,
                                                 const float* __restrict__ b1,
                                                 float* __restrict__ h1r, int n) {
    long long g = (long long)blockIdx.x * blockDim.x + threadIdx.x;
    int node = (int)(g >> 5);
    int ch = (int)(g & 31);
    if (node >= n) return;
    float acc = h1s[(long long)node * HIDC + ch];   // self-loop term (x dinv already)
    int st = ptr[node], deg = cnt[node];
    int j = 0;
    for (; j + 3 < deg; j += 4) {
        int s0 = csr_src[st + j], s1 = csr_src[st + j + 1];
        int s2 = csr_src[st + j + 2], s3 = csr_src[st + j + 3];
        float a0 = h1s[(long long)s0 * HIDC + ch];
        float a1 = h1s[(long long)s1 * HIDC + ch];
        float a2 = h1s[(long long)s2 * HIDC + ch];
        float a3 = h1s[(long long)s3 * HIDC + ch];
        acc += (a0 + a1) + (a2 + a3);
    }
    for (; j < deg; ++j)
        acc += h1s[(long long)csr_src[st + j] * HIDC + ch];
    float v = acc * dinv[node] + b1[ch];
    h1r[(long long)node * HIDC + ch] = v > 0.f ? v : 0.f;
}

// ---------------- gemm2: h2s = (h1r @ W2) * dinv  [n,32]x[32,16] ------------
__global__ __launch_bounds__(256) void k_gemm2(const float* __restrict__ h1,
                                               const float* __restrict__ W2,
                                               const float* __restrict__ dinv,
                                               float* __restrict__ h2s, int n) {
    int node = blockIdx.x * 256 + threadIdx.x;
    if (node >= n) return;
    float xr[HIDC];
#pragma unroll
    for (int j = 0; j < 8; ++j) {
        float4 v = *(const float4*)(h1 + (long long)node * HIDC + j * 4);
        xr[j * 4 + 0] = v.x; xr[j * 4 + 1] = v.y;
        xr[j * 4 + 2] = v.z; xr[j * 4 + 3] = v.w;
    }
    float acc[OUTC];
#pragma unroll
    for (int o = 0; o < OUTC; ++o) acc[o] = 0.f;
#pragma unroll
    for (int kk = 0; kk < HIDC; ++kk) {
        const float* __restrict__ wrow = W2 + kk * OUTC;
#pragma unroll
        for (int o = 0; o < OUTC; ++o)
            acc[o] = fmaf(xr[kk], wrow[o], acc[o]);
    }
    float di = dinv[node];
#pragma unroll
    for (int j = 0; j < 4; ++j)
        *(float4*)(h2s + (long long)node * OUTC + j * 4) =
            make_float4(acc[j * 4] * di, acc[j * 4 + 1] * di,
                        acc[j * 4 + 2] * di, acc[j * 4 + 3] * di);
}

// ---------------- layer-2 pull aggregation + fused finalize ----------------
// quarter-wave (16 lanes = 16 ch) per dst node; writes d_out directly.
__global__ __launch_bounds__(256) void k_agg2csr(const int* __restrict__ ptr,
                                                 const int* __restrict__ cnt,
                                                 const int* __restrict__ csr_src,
                                                 const float* __restrict__ dinv,
                                                 const float* __restrict__ h2s,
                                                 const float* __restrict__ b2,
                                                 float* __restrict__ out, int n) {
    long long g = (long long)blockIdx.x * blockDim.x + threadIdx.x;
    int node = (int)(g >> 4);
    int ch = (int)(g & 15);
    if (node >= n) return;
    float acc = h2s[(long long)node * OUTC + ch];
    int st = ptr[node], deg = cnt[node];
    int j = 0;
    for (; j + 3 < deg; j += 4) {
        int s0 = csr_src[st + j], s1 = csr_src[st + j + 1];
        int s2 = csr_src[st + j + 2], s3 = csr_src[st + j + 3];
        float a0 = h2s[(long long)s0 * OUTC + ch];
        float a1 = h2s[(long long)s1 * OUTC + ch];
        float a2 = h2s[(long long)s2 * OUTC + ch];
        float a3 = h2s[(long long)s3 * OUTC + ch];
        acc += (a0 + a1) + (a2 + a3);
    }
    for (; j < deg; ++j)
        acc += h2s[(long long)csr_src[st + j] * OUTC + ch];
    out[(long long)node * OUTC + ch] = acc * dinv[node] + b2[ch];
}

extern "C" void kernel_launch(void* const* d_in, const int* in_sizes, int n_in,
                              void* d_out, int out_size, void* d_ws, size_t ws_size,
                              hipStream_t stream) {
    const float* x  = (const float*)d_in[0];
    const int*   ei = (const int*)d_in[1];
    const float* W1 = (const float*)d_in[2];
    const float* b1 = (const float*)d_in[3];
    const float* W2 = (const float*)d_in[4];
    const float* b2 = (const float*)d_in[5];
    const int n = in_sizes[0] / IN_C;            // 100000
    const long long E = in_sizes[1] / 2;         // 3200000
    float* out = (float*)d_out;

    const int nbkt = (n + NPB - 1) / NPB;        // 782

    char* ws = (char*)d_ws;
    size_t off = 0;
    auto alloc = [&](size_t bytes) { void* p = ws + off; off += (bytes + 255) & ~(size_t)255; return p; };
    int*      flag     = (int*)alloc(256);
    int*      bkt_cnt  = (int*)alloc((size_t)MAXBKT * 4);
    int*      bkt_base = (int*)alloc((size_t)MAXBKT * 4);
    int*      bkt_cur  = (int*)alloc((size_t)MAXBKT * 4);
    float*    dinv     = (float*)alloc((size_t)n * 4);
    int*      cnt      = (int*)alloc((size_t)n * 4);
    int*      ptr      = (int*)alloc((size_t)n * 4);
    unsigned* packed   = (unsigned*)alloc((size_t)E * 4);
    int*      csr_src  = (int*)alloc((size_t)E * 4);
    float*    h1s      = (float*)alloc((size_t)n * HIDC * 4);
    float*    h1r      = (float*)alloc((size_t)n * HIDC * 4);
    float*    h2s      = h1s;  // h1s dead after k_agg1csr; reuse

    hipMemsetAsync(bkt_cnt, 0, (size_t)nbkt * 4, stream);

    k_detect<<<1, 256, 0, stream>>>(ei, flag);
    k_bin_count<<<256, 256, 0, stream>>>(ei, E, flag, bkt_cnt, nbkt);
    k_bscan<<<1, 512, 0, stream>>>(bkt_cnt, bkt_base, bkt_cur, nbkt);
    k_bin_scatter<<<256, 256, 0, stream>>>(ei, E, flag, bkt_cur, packed, nbkt);
    k_bucket_csr<<<nbkt, 256, 0, stream>>>(packed, bkt_base, bkt_cnt, csr_src, ptr, cnt, dinv, n);

    k_gemm1<<<(n + 255) / 256, 256, 0, stream>>>(x, W1, dinv, h1s, n);
    k_agg1csr<<<(int)(((long long)n * HIDC + 255) / 256), 256, 0, stream>>>(
        ptr, cnt, csr_src, dinv, h1s, b1, h1r, n);
    k_gemm2<<<(n + 255) / 256, 256, 0, stream>>>(h1r, W2, dinv, h2s, n);
    k_agg2csr<<<(int)(((long long)n * OUTC + 255) / 256), 256, 0, stream>>>(
        ptr, cnt, csr_src, dinv, h2s, b2, out, n);
}